// Round 1
// baseline (147.002 us; speedup 1.0000x reference)
//
#include <hip/hip_runtime.h>
#include <hip/hip_bf16.h>

// Problem constants (B=2, S=2048, E=1024, H=16, Dh=64)
#define S_LEN 2048
#define EMB   1024
#define NH    16
#define DH    64
#define QKV_LD 3072   // 3*EMB

typedef __attribute__((ext_vector_type(8)))  __bf16 bf16x8;
typedef __attribute__((ext_vector_type(4)))  __bf16 bf16x4;
typedef __attribute__((ext_vector_type(4)))  float  f32x4;
typedef __attribute__((ext_vector_type(16))) float  f32x16;
typedef __attribute__((ext_vector_type(2)))  unsigned int u32x2;

// ---- async global->LDS (16B per lane; LDS dst = wave-uniform base) ----
__device__ __forceinline__ void gl_lds16(const void* g, void* l) {
  __builtin_amdgcn_global_load_lds(
      (const __attribute__((address_space(1))) void*)g,
      (__attribute__((address_space(3))) void*)l,
      16, 0, 0);
}

// ---------------- fused prep: cast x -> bf16, transpose+cast both weights --
__global__ __launch_bounds__(256)
void prep_fused(const float* __restrict__ x, __bf16* __restrict__ xb,
                const float* __restrict__ w_attn, __bf16* __restrict__ wat,
                const float* __restrict__ w_proj, __bf16* __restrict__ wpt,
                int n8) {
  __shared__ float T[64][65];
  const int bid = blockIdx.x;
  const int tid = threadIdx.x;

  if (bid < 2048) {
    int i = bid * 256 + tid;
    if (i >= n8) return;
    const f32x4* p = (const f32x4*)(x + (size_t)i * 8);
    f32x4 a = p[0], b = p[1];
    bf16x8 o;
    #pragma unroll
    for (int j = 0; j < 4; j++) { o[j] = (__bf16)a[j]; o[4 + j] = (__bf16)b[j]; }
    *(bf16x8*)(xb + (size_t)i * 8) = o;
    return;
  }

  const float* W; __bf16* Wt; int K, N, k0, n0;
  if (bid < 2048 + 768) {
    int t = bid - 2048;                 // w_attn: N=3072 -> 48 x-tiles, 16 k-tiles
    W = w_attn; Wt = wat; K = 1024; N = 3072;
    n0 = (t % 48) * 64; k0 = (t / 48) * 64;
  } else {
    int t = bid - 2816;                 // w_proj: 16 x 16 tiles
    W = w_proj; Wt = wpt; K = 1024; N = 1024;
    n0 = (t & 15) * 64; k0 = (t >> 4) * 64;
  }
  #pragma unroll
  for (int t = 0; t < 16; t++) {
    int idx = tid + t * 256;
    int r = idx >> 6, c = idx & 63;
    T[r][c] = W[(size_t)(k0 + r) * N + n0 + c];
  }
  __syncthreads();
  #pragma unroll
  for (int t = 0; t < 16; t++) {
    int idx = tid + t * 256;
    int r = idx >> 6, c = idx & 63;     // r = local n, c = local k
    Wt[(size_t)(n0 + r) * K + k0 + c] = (__bf16)T[c][r];
  }
}

// ---------------- bf16 MFMA GEMM: C(MxN) = A(MxK) @ Bt(NxK)^T -------------
#define TM 128
#define TK 32

template <typename OutT, int TNv>
__global__ __launch_bounds__(256, 2)
void gemm_bf16_mfma(const __bf16* __restrict__ A, const __bf16* __restrict__ Bt,
                    OutT* __restrict__ C, int M, int N, int K) {
  __shared__ __align__(16) __bf16 As[2][TM][TK];
  __shared__ __align__(16) __bf16 Bs[2][TNv][TK];
  const int tid  = threadIdx.x;
  const int lane = tid & 63;
  const int w    = tid >> 6;
  const int wr   = w >> 1, wc = w & 1;
  const int brow = blockIdx.y * TM;
  const int bcol = blockIdx.x * TNv;
  const int l15  = lane & 15;
  const int grp  = lane >> 4;

  constexpr int NBI = TNv / 64;        // B staging issues per wave
  constexpr int WCT = TNv / 2;         // wave column tile
  constexpr int NN  = WCT / 16;        // n-fragments per wave

  auto stage = [&](int k0, int buf) {
    #pragma unroll
    for (int j = 0; j < 2; j++) {       // A: 128x32 = 512 chunks, 2/wave
      const int cid = w * 128 + j * 64 + lane;
      const int row = cid >> 2, k8 = (cid & 3) * 8;
      gl_lds16(A + (size_t)(brow + row) * K + k0 + k8,
               &As[buf][0][0] + (size_t)(w * 128 + j * 64) * 8);
    }
    #pragma unroll
    for (int j = 0; j < NBI; j++) {     // B: TNv x 32 chunks
      const int cid = (w * NBI + j) * 64 + lane;
      const int row = cid >> 2, k8 = (cid & 3) * 8;
      gl_lds16(Bt + (size_t)(bcol + row) * K + k0 + k8,
               &Bs[buf][0][0] + (size_t)((w * NBI + j) * 64) * 8);
    }
  };

  f32x4 acc[4][NN];
  #pragma unroll
  for (int m = 0; m < 4; m++)
    #pragma unroll
    for (int n = 0; n < NN; n++) acc[m][n] = (f32x4){0.f, 0.f, 0.f, 0.f};

  stage(0, 0);
  __syncthreads();                      // drains prologue vmcnt

  const int nk = K / TK;
  for (int kt = 0; kt < nk; kt++) {
    const int cur = kt & 1;
    if (kt + 1 < nk) stage((kt + 1) * TK, cur ^ 1);   // prefetch under MFMA

    bf16x8 a[4], b[NN];
    #pragma unroll
    for (int m = 0; m < 4; m++)
      a[m] = *(const bf16x8*)&As[cur][wr * 64 + m * 16 + l15][grp * 8];
    #pragma unroll
    for (int n = 0; n < NN; n++)
      b[n] = *(const bf16x8*)&Bs[cur][wc * WCT + n * 16 + l15][grp * 8];
    #pragma unroll
    for (int m = 0; m < 4; m++)
      #pragma unroll
      for (int n = 0; n < NN; n++)
        acc[m][n] = __builtin_amdgcn_mfma_f32_16x16x32_bf16(a[m], b[n], acc[m][n], 0, 0, 0);

    __syncthreads();   // all waves done reading cur; prefetch landed
  }

  #pragma unroll
  for (int m = 0; m < 4; m++)
    #pragma unroll
    for (int r = 0; r < 4; r++) {
      const size_t row = (size_t)(brow + wr * 64 + m * 16 + grp * 4 + r);
      #pragma unroll
      for (int n = 0; n < NN; n++)
        C[row * N + bcol + wc * WCT + n * 16 + l15] = (OutT)acc[m][n][r];
    }
}

// ---------------- MFMA flash attention v14: split-K -----------------------
// Same 4-wave 64x64 tile engine as v13 (32x32 MFMA, (qh,kh) wave split,
// chunk-XOR K swizzle, tr_read V, exp2/defer-max, setprio), but the causal
// triangle is re-cut so NO block runs more than 16 K-tile iterations:
//   qtile 0..15  -> 1 block,   1..16 iters, writes y directly (normalized)
//   qtile 16..31 -> 2 blocks (K-halves, 8..16 iters each), each writes an
//                   UNNORMALIZED partial (m, l, O f32); attn_merge combines.
// v13's critical path was 32 serial iterations (~3300 cyc each = 44 us);
// splitting halves the chain and lifts residency to ~5 blocks/CU.
// Item decode is longest-first within each XCD so the dispatch queue
// backfills with short items. L2 grouping (4 (b,h) groups per XCD) kept.
#define QB 64
#define KB 64
#define QSCALE 0.18033688f   // 0.125 * log2(e)

__global__ __launch_bounds__(256, 5)
void attn_mfma(const __bf16* __restrict__ qkv, __bf16* __restrict__ y,
               float* __restrict__ pO, float* __restrict__ pml) {
  __shared__ __align__(16) __bf16 Ks[2][KB][64];   // 16 KB
  __shared__ __align__(16) __bf16 Vs[2][4096];     // 16 KB

  const int tid  = threadIdx.x;
  const int lane = tid & 63;
  const int w    = tid >> 6;

  // ---- work-item decode: 1536 blocks = 8 XCD x 4 groups x 48 items ----
  // idx -> (t = idx/3, r3 = idx%3): r3<2 = split half of qtile 31-t,
  // r3==2 = unsplit qtile 15-t.  Lengths descend with idx (LPT order).
  const int bid = blockIdx.x;                 // 0..1535
  const int xcd = bid & 7;
  const int j   = bid >> 3;                   // 0..191
  const int g   = xcd * 4 + j / 48;           // (b,h) group 0..31
  const int idx = j % 48;
  const int t3  = idx / 3, r3 = idx - t3 * 3;

  int qtile, it0, it1, khalf;
  bool split, diag;
  if (r3 == 2) {                              // unsplit small qtile
    qtile = 15 - t3; split = false; khalf = 0;
    it0 = 0; it1 = qtile + 1; diag = true;
  } else {                                    // K-half of a large qtile
    qtile = 31 - t3; split = true; khalf = r3;
    const int half = (qtile + 2) >> 1;        // ceil((qtile+1)/2)
    it0 = khalf ? half : 0;
    it1 = khalf ? qtile + 1 : half;
    diag = (khalf == 1);
  }
  const int h = g & 15, b = g >> 4;
  const int pidx = split ? ((g * 16 + (qtile - 16)) * 2 + khalf) : 0;

  const __bf16* base = qkv + (size_t)b * S_LEN * QKV_LD;

  const int l31 = lane & 31;
  const int hl  = lane >> 5;          // lane half (0/1)
  const int qh  = w >> 1;             // q-half of the 64-row tile
  const int kh  = w & 1;              // k-half of each 64-key tile

  // tr_read per-lane base: column (lane&15) of the [4][16] subtile; the
  // db/sk selection comes from the address (law verified against v10).
  const int voff32 = ((lane >> 4) & 1) * 2048 + hl * 128 + (lane & 15) * 8
                   + kh * 1024;

  auto stageK = [&](int j0, int buf) {
    #pragma unroll
    for (int jj = 0; jj < 2; jj++) {
      const int cid = w * 128 + jj * 64 + lane;    // chunk 0..511
      const int r = cid >> 3, pc = cid & 7;
      const int lc = pc ^ (r & 7);                 // inverse swizzle on source
      gl_lds16(base + (size_t)(j0 + r) * QKV_LD + EMB + h * DH + lc * 8,
               (char*)&Ks[buf][0][0] + (w * 128 + jj * 64) * 16);
    }
  };
  auto stageV = [&](int j0, int buf) {
    #pragma unroll
    for (int jj = 0; jj < 2; jj++) {
      const int cid = w * 128 + jj * 64 + lane;
      const int db = cid >> 7, sk = (cid >> 3) & 15;
      const int jr = (cid >> 1) & 3, ch = cid & 1;
      gl_lds16(base + (size_t)(j0 + sk * 4 + jr) * QKV_LD + 2 * EMB + h * DH
                    + db * 16 + ch * 8,
               (char*)&Vs[buf][0] + (w * 128 + jj * 64) * 16);
    }
  };

  const int qbase = qtile * QB;
  const int q = qbase + qh * 32 + l31;           // this lane's q row

  // Q B-fragments (col=q, k_hw=d): qf[dq][i] = Q[q][dq*16 + hl*8 + i]
  bf16x8 qf[4];
  {
    const __bf16* qp = base + (size_t)q * QKV_LD + h * DH;
    #pragma unroll
    for (int dq = 0; dq < 4; dq++) {
      bf16x8 v = *(const bf16x8*)(qp + dq * 16 + hl * 8);
      #pragma unroll
      for (int i2 = 0; i2 < 8; i2++) qf[dq][i2] = (__bf16)((float)v[i2] * QSCALE);
    }
  }

  f32x16 o_acc[2];
  #pragma unroll
  for (int d2 = 0; d2 < 2; d2++)
    #pragma unroll
    for (int r = 0; r < 16; r++) o_acc[d2][r] = 0.f;
  float m = -1e30f, l = 0.f;

  // Process one K-tile: QK^T -> (masked?) online softmax -> PV.
  auto process = [&](int cur, int j0, bool masked) {
    // ---- S^T = K Q (32k x 32q, chained over d) ----
    // s[reg]: k = j0 + kh*32 + (reg&3) + 8*(reg>>2) + 4*hl, q = l31.
    f32x16 s;
    #pragma unroll
    for (int r = 0; r < 16; r++) s[r] = 0.f;
    const int krow = kh * 32 + l31;
    __builtin_amdgcn_s_setprio(1);
    #pragma unroll
    for (int dq = 0; dq < 4; dq++) {
      bf16x8 kf = *(const bf16x8*)&Ks[cur][krow][((dq * 2 + hl) ^ (krow & 7)) * 8];
      s = __builtin_amdgcn_mfma_f32_32x32x16_bf16(kf, qf[dq], s, 0, 0, 0);
    }
    __builtin_amdgcn_s_setprio(0);

    if (masked) {
      const int lim = q - j0 - kh * 32 - 4 * hl;   // keep if (reg&3)+8*(reg>>2) <= lim
      #pragma unroll
      for (int r = 0; r < 16; r++) {
        const int kl = (r & 3) + 8 * (r >> 2);
        if (kl > lim) s[r] = -2e30f;    // -2e30: exp2(s-m)==0 even when m=-1e30
      }
    }

    // ---- max reduce (in-lane tree + ONE cross-half shuffle) ----
    float tmax = s[0];
    #pragma unroll
    for (int r = 1; r < 16; r++) tmax = fmaxf(tmax, s[r]);
    tmax = fmaxf(tmax, __shfl_xor(tmax, 32));

    const bool grow = !__all(tmax <= m + 8.0f);
    float corr = 1.f;
    if (grow) {
      const float mnew = fmaxf(m, tmax);
      corr = __builtin_amdgcn_exp2f(m - mnew);
      m = mnew;
    }

    // ---- issue all 8 V^T transpose reads; latency hides under exp phase ----
    // read t = dblk*4 + kchain*2 + r at offset dblk*4096 + kchain*512 + r*256
    const unsigned vb =
        (unsigned)(uintptr_t)(__attribute__((address_space(3))) char*)(&Vs[cur][0])
        + (unsigned)voff32;
    u32x2 tv[8];
    asm volatile("ds_read_b64_tr_b16 %0, %1 offset:0"    : "=v"(tv[0]) : "v"(vb));
    asm volatile("ds_read_b64_tr_b16 %0, %1 offset:256"  : "=v"(tv[1]) : "v"(vb));
    asm volatile("ds_read_b64_tr_b16 %0, %1 offset:512"  : "=v"(tv[2]) : "v"(vb));
    asm volatile("ds_read_b64_tr_b16 %0, %1 offset:768"  : "=v"(tv[3]) : "v"(vb));
    asm volatile("ds_read_b64_tr_b16 %0, %1 offset:4096" : "=v"(tv[4]) : "v"(vb));
    asm volatile("ds_read_b64_tr_b16 %0, %1 offset:4352" : "=v"(tv[5]) : "v"(vb));
    asm volatile("ds_read_b64_tr_b16 %0, %1 offset:4608" : "=v"(tv[6]) : "v"(vb));
    asm volatile("ds_read_b64_tr_b16 %0, %1 offset:4864" : "=v"(tv[7]) : "v"(vb));

    // ---- exp2 + in-lane psum (VALU; covers the tr_read latency) ----
    float psum = 0.f;
    #pragma unroll
    for (int r = 0; r < 16; r++) {
      float p = __builtin_amdgcn_exp2f(s[r] - m);
      s[r] = p;
      psum += p;
    }

    // ---- P^T B-frags: fully in-lane (shared sigma with the A-side) ----
    bf16x8 pb0, pb1;
    #pragma unroll
    for (int i2 = 0; i2 < 8; i2++) {
      pb0[i2] = (__bf16)s[i2];
      pb1[i2] = (__bf16)s[8 + i2];
    }

    // ---- O-rescale must precede PV; l-update deferred past PV ----
    if (grow) {
      #pragma unroll
      for (int d2 = 0; d2 < 2; d2++)
        #pragma unroll
        for (int r = 0; r < 16; r++) o_acc[d2][r] *= corr;
    }

    // ---- single drain, then 4 back-to-back PV MFMAs ----
    asm volatile("s_waitcnt lgkmcnt(0)");
    __builtin_amdgcn_sched_barrier(0);
    __builtin_amdgcn_s_setprio(1);
    #pragma unroll
    for (int d2 = 0; d2 < 2; d2++) {
      bf16x8 a0, a1;
      ((u32x2*)&a0)[0] = tv[d2 * 4 + 0]; ((u32x2*)&a0)[1] = tv[d2 * 4 + 1];
      ((u32x2*)&a1)[0] = tv[d2 * 4 + 2]; ((u32x2*)&a1)[1] = tv[d2 * 4 + 3];
      o_acc[d2] = __builtin_amdgcn_mfma_f32_32x32x16_bf16(a0, pb0, o_acc[d2], 0, 0, 0);
      o_acc[d2] = __builtin_amdgcn_mfma_f32_32x32x16_bf16(a1, pb1, o_acc[d2], 0, 0, 0);
    }
    __builtin_amdgcn_s_setprio(0);

    // ---- l-update (off the PV critical path) ----
    psum += __shfl_xor(psum, 32);
    l = grow ? (l * corr + psum) : (l + psum);
  };

  // prologue: stage first tile of this item's K-range
  stageK(it0 * KB, 0);
  stageV(it0 * KB, 0);
  __syncthreads();

  // main loop: iterations it0..it1-2 unmasked, prefetching next
  const int nt = it1 - it0;
  #pragma unroll 1
  for (int tt = 0; tt < nt - 1; tt++) {
    const int cur = tt & 1;
    stageK((it0 + tt + 1) * KB, cur ^ 1);
    stageV((it0 + tt + 1) * KB, cur ^ 1);
    process(cur, (it0 + tt) * KB, false);
    __syncthreads();   // staged loads drained; buf cur free for reuse
  }

  // final tile (masked iff this item covers the diagonal)
  process((nt - 1) & 1, (it1 - 1) * KB, diag);

  // ---- kh-pair merge through LDS, then epilogue by kh=0 waves ----
  __syncthreads();     // all waves done with Ks/Vs; reuse as exchange space
  float* exO  = (float*)&Vs[0][0];      // [32 rows][128 slots] f32 = 16 KB
  float* exML = (float*)&Ks[0][0][0];   // [2][128] f32
  const int slot = qh * 64 + lane;
  if (kh) {
    #pragma unroll
    for (int r = 0; r < 16; r++) {
      exO[r * 128 + slot]        = o_acc[0][r];
      exO[(16 + r) * 128 + slot] = o_acc[1][r];
    }
    exML[slot]       = m;
    exML[128 + slot] = l;
  }
  __syncthreads();
  if (!kh) {
    const float m1  = exML[slot];
    const float l1v = exML[128 + slot];
    const float mm = fmaxf(m, m1);
    const float c0 = __builtin_amdgcn_exp2f(m - mm);
    const float c1 = __builtin_amdgcn_exp2f(m1 - mm);
    const float lsum = l * c0 + l1v * c1;
    if (split) {
      // unnormalized f32 partial + (m,l) for attn_merge
      float* prow = pO + (size_t)pidx * 4096 + (size_t)(qh * 32 + l31) * 64;
      #pragma unroll
      for (int d2 = 0; d2 < 2; d2++)
        #pragma unroll
        for (int rq = 0; rq < 4; rq++) {
          f32x4 o4;
          #pragma unroll
          for (int jj = 0; jj < 4; jj++) {
            const int r = rq * 4 + jj;
            o4[jj] = o_acc[d2][r] * c0 + exO[(d2 * 16 + r) * 128 + slot] * c1;
          }
          *(f32x4*)&prow[d2 * 32 + rq * 8 + hl * 4] = o4;
        }
      if (!hl) {
        pml[(size_t)pidx * 128 + qh * 32 + l31]      = mm;
        pml[(size_t)pidx * 128 + 64 + qh * 32 + l31] = lsum;
      }
    } else {
      const float inv = 1.f / lsum;
      __bf16* yrow = y + ((size_t)(b * S_LEN + q)) * EMB + h * DH;
      #pragma unroll
      for (int d2 = 0; d2 < 2; d2++)
        #pragma unroll
        for (int rq = 0; rq < 4; rq++) {
          bf16x4 o4;
          #pragma unroll
          for (int jj = 0; jj < 4; jj++) {
            const int r = rq * 4 + jj;
            float v = (o_acc[d2][r] * c0 + exO[(d2 * 16 + r) * 128 + slot] * c1) * inv;
            o4[jj] = (__bf16)v;
          }
          // d = d2*32 + rq*8 + hl*4 + jj
          *(bf16x4*)&yrow[d2 * 32 + rq * 8 + hl * 4] = o4;
        }
    }
  }
}

// ---------------- merge the two K-half partials of qtiles 16..31 ----------
__global__ __launch_bounds__(256)
void attn_merge(const float* __restrict__ pO, const float* __restrict__ pml,
                __bf16* __restrict__ y) {
  const int mid = blockIdx.x;            // 0..511
  const int g = mid >> 4, qrel = mid & 15;
  const int qt = 16 + qrel;
  const int b = g >> 4, h = g & 15;
  const int p0 = (g * 16 + qrel) * 2, p1 = p0 + 1;
  const int row = threadIdx.x >> 2;            // 0..63
  const int d0  = (threadIdx.x & 3) * 16;      // 0,16,32,48

  const float mA = pml[(size_t)p0 * 128 + row];
  const float lA = pml[(size_t)p0 * 128 + 64 + row];
  const float mB = pml[(size_t)p1 * 128 + row];
  const float lB = pml[(size_t)p1 * 128 + 64 + row];
  const float mm = fmaxf(mA, mB);
  const float cA = __builtin_amdgcn_exp2f(mA - mm);
  const float cB = __builtin_amdgcn_exp2f(mB - mm);
  const float inv = 1.f / (lA * cA + lB * cB);

  const float* OA = pO + (size_t)p0 * 4096 + (size_t)row * 64 + d0;
  const float* OB = pO + (size_t)p1 * 4096 + (size_t)row * 64 + d0;
  __bf16* yr = y + ((size_t)(b * S_LEN + qt * 64 + row)) * EMB + h * DH + d0;
  #pragma unroll
  for (int i = 0; i < 4; i++) {
    f32x4 va = *(const f32x4*)(OA + i * 4);
    f32x4 vb = *(const f32x4*)(OB + i * 4);
    bf16x4 o;
    #pragma unroll
    for (int jj = 0; jj < 4; jj++)
      o[jj] = (__bf16)((va[jj] * cA + vb[jj] * cB) * inv);
    *(bf16x4*)(yr + i * 4) = o;
  }
}

// ---------------- Launch ----------------
extern "C" void kernel_launch(void* const* d_in, const int* in_sizes, int n_in,
                              void* d_out, int out_size, void* d_ws, size_t ws_size,
                              hipStream_t stream) {
  const float* x      = (const float*)d_in[0];  // (B, S, E)
  const float* w_attn = (const float*)d_in[1];  // (E, 3E)
  const float* w_proj = (const float*)d_in[2];  // (E, E)
  float* out = (float*)d_out;                   // (B, S, E)

  const int B = in_sizes[0] / (S_LEN * EMB);    // = 2
  const int M = B * S_LEN;                      // 4096

  // bf16 workspace layout
  __bf16* xb   = (__bf16*)d_ws;                       // M x E
  __bf16* wat  = xb  + (size_t)M * EMB;               // 3E x E (transposed)
  __bf16* wpt  = wat + (size_t)QKV_LD * EMB;          // E x E (transposed)
  __bf16* qkvb = wpt + (size_t)EMB * EMB;             // M x 3E
  __bf16* yb   = qkvb + (size_t)M * QKV_LD;           // M x E

  // split-K scratch: partial O (1024 x 64 x 64 f32 = 16 MB) fits EXACTLY in
  // d_out (dead until gemm3 writes it); (m,l) reuses wat (dead after gemm1).
  float* pO  = out;
  float* pml = (float*)wat;

  // 0) fused prep: cast + both weight transposes in one launch
  {
    int n8 = (M * EMB) / 8;   // 524288 -> 2048 cast blocks
    prep_fused<<<dim3(3072), 256, 0, stream>>>(x, xb, w_attn, wat, w_proj, wpt, n8);
  }

  // 1) qkv = x @ w_attn  (bf16 out, TN=128: grid 768 = 3 blocks/CU)
  dim3 g1(QKV_LD / 128, M / TM);
  gemm_bf16_mfma<__bf16, 128><<<g1, 256, 0, stream>>>(xb, wat, qkvb, M, QKV_LD, EMB);

  // 2) y = causal_attention(qkv)  [v14: split-K, <=16 iters/block]
  attn_mfma<<<dim3(1536), 256, 0, stream>>>(qkvb, yb, pO, pml);
  attn_merge<<<dim3(512), 256, 0, stream>>>(pO, pml, yb);

  // 3) out = y @ w_proj  (f32 out, TN=64: grid 512 = 2 blocks/CU)
  dim3 g3(EMB / 64, M / TM);
  gemm_bf16_mfma<float, 64><<<g3, 256, 0, stream>>>(yb, wpt, out, M, EMB, EMB);
}

// Round 2
// 111.108 us; speedup vs baseline: 1.3231x; 1.3231x over previous
//
#include <hip/hip_runtime.h>
#include <hip/hip_bf16.h>

// Problem constants (B=2, S=2048, E=1024, H=16, Dh=64)
#define S_LEN 2048
#define EMB   1024
#define NH    16
#define DH    64
#define QKV_LD 3072   // 3*EMB

typedef __attribute__((ext_vector_type(8)))  __bf16 bf16x8;
typedef __attribute__((ext_vector_type(4)))  __bf16 bf16x4;
typedef __attribute__((ext_vector_type(4)))  float  f32x4;
typedef __attribute__((ext_vector_type(16))) float  f32x16;
typedef __attribute__((ext_vector_type(2)))  unsigned int u32x2;

// ---- async global->LDS (16B per lane; LDS dst = wave-uniform base) ----
__device__ __forceinline__ void gl_lds16(const void* g, void* l) {
  __builtin_amdgcn_global_load_lds(
      (const __attribute__((address_space(1))) void*)g,
      (__attribute__((address_space(3))) void*)l,
      16, 0, 0);
}

// ---------------- fused prep: cast x -> bf16, transpose+cast both weights --
__global__ __launch_bounds__(256)
void prep_fused(const float* __restrict__ x, __bf16* __restrict__ xb,
                const float* __restrict__ w_attn, __bf16* __restrict__ wat,
                const float* __restrict__ w_proj, __bf16* __restrict__ wpt,
                int n8) {
  __shared__ float T[64][65];
  const int bid = blockIdx.x;
  const int tid = threadIdx.x;

  if (bid < 2048) {
    int i = bid * 256 + tid;
    if (i >= n8) return;
    const f32x4* p = (const f32x4*)(x + (size_t)i * 8);
    f32x4 a = p[0], b = p[1];
    bf16x8 o;
    #pragma unroll
    for (int j = 0; j < 4; j++) { o[j] = (__bf16)a[j]; o[4 + j] = (__bf16)b[j]; }
    *(bf16x8*)(xb + (size_t)i * 8) = o;
    return;
  }

  const float* W; __bf16* Wt; int K, N, k0, n0;
  if (bid < 2048 + 768) {
    int t = bid - 2048;                 // w_attn: N=3072 -> 48 x-tiles, 16 k-tiles
    W = w_attn; Wt = wat; K = 1024; N = 3072;
    n0 = (t % 48) * 64; k0 = (t / 48) * 64;
  } else {
    int t = bid - 2816;                 // w_proj: 16 x 16 tiles
    W = w_proj; Wt = wpt; K = 1024; N = 1024;
    n0 = (t & 15) * 64; k0 = (t >> 4) * 64;
  }
  #pragma unroll
  for (int t = 0; t < 16; t++) {
    int idx = tid + t * 256;
    int r = idx >> 6, c = idx & 63;
    T[r][c] = W[(size_t)(k0 + r) * N + n0 + c];
  }
  __syncthreads();
  #pragma unroll
  for (int t = 0; t < 16; t++) {
    int idx = tid + t * 256;
    int r = idx >> 6, c = idx & 63;     // r = local n, c = local k
    Wt[(size_t)(n0 + r) * K + k0 + c] = (__bf16)T[c][r];
  }
}

// ---------------- bf16 MFMA GEMM: C(MxN) = A(MxK) @ Bt(NxK)^T -------------
#define TM 128
#define TK 32

template <typename OutT, int TNv>
__global__ __launch_bounds__(256, 2)
void gemm_bf16_mfma(const __bf16* __restrict__ A, const __bf16* __restrict__ Bt,
                    OutT* __restrict__ C, int M, int N, int K) {
  __shared__ __align__(16) __bf16 As[2][TM][TK];
  __shared__ __align__(16) __bf16 Bs[2][TNv][TK];
  const int tid  = threadIdx.x;
  const int lane = tid & 63;
  const int w    = tid >> 6;
  const int wr   = w >> 1, wc = w & 1;
  const int brow = blockIdx.y * TM;
  const int bcol = blockIdx.x * TNv;
  const int l15  = lane & 15;
  const int grp  = lane >> 4;

  constexpr int NBI = TNv / 64;        // B staging issues per wave
  constexpr int WCT = TNv / 2;         // wave column tile
  constexpr int NN  = WCT / 16;        // n-fragments per wave

  auto stage = [&](int k0, int buf) {
    #pragma unroll
    for (int j = 0; j < 2; j++) {       // A: 128x32 = 512 chunks, 2/wave
      const int cid = w * 128 + j * 64 + lane;
      const int row = cid >> 2, k8 = (cid & 3) * 8;
      gl_lds16(A + (size_t)(brow + row) * K + k0 + k8,
               &As[buf][0][0] + (size_t)(w * 128 + j * 64) * 8);
    }
    #pragma unroll
    for (int j = 0; j < NBI; j++) {     // B: TNv x 32 chunks
      const int cid = (w * NBI + j) * 64 + lane;
      const int row = cid >> 2, k8 = (cid & 3) * 8;
      gl_lds16(Bt + (size_t)(bcol + row) * K + k0 + k8,
               &Bs[buf][0][0] + (size_t)((w * NBI + j) * 64) * 8);
    }
  };

  f32x4 acc[4][NN];
  #pragma unroll
  for (int m = 0; m < 4; m++)
    #pragma unroll
    for (int n = 0; n < NN; n++) acc[m][n] = (f32x4){0.f, 0.f, 0.f, 0.f};

  stage(0, 0);
  __syncthreads();                      // drains prologue vmcnt

  const int nk = K / TK;
  for (int kt = 0; kt < nk; kt++) {
    const int cur = kt & 1;
    if (kt + 1 < nk) stage((kt + 1) * TK, cur ^ 1);   // prefetch under MFMA

    bf16x8 a[4], b[NN];
    #pragma unroll
    for (int m = 0; m < 4; m++)
      a[m] = *(const bf16x8*)&As[cur][wr * 64 + m * 16 + l15][grp * 8];
    #pragma unroll
    for (int n = 0; n < NN; n++)
      b[n] = *(const bf16x8*)&Bs[cur][wc * WCT + n * 16 + l15][grp * 8];
    #pragma unroll
    for (int m = 0; m < 4; m++)
      #pragma unroll
      for (int n = 0; n < NN; n++)
        acc[m][n] = __builtin_amdgcn_mfma_f32_16x16x32_bf16(a[m], b[n], acc[m][n], 0, 0, 0);

    __syncthreads();   // all waves done reading cur; prefetch landed
  }

  #pragma unroll
  for (int m = 0; m < 4; m++)
    #pragma unroll
    for (int r = 0; r < 4; r++) {
      const size_t row = (size_t)(brow + wr * 64 + m * 16 + grp * 4 + r);
      #pragma unroll
      for (int n = 0; n < NN; n++)
        C[row * N + bcol + wc * WCT + n * 16 + l15] = (OutT)acc[m][n][r];
    }
}

// ---------------- MFMA flash attention v15: split-K, cached partials ------
// v14 post-mortem: using d_out as pO scratch hit an uncached/fine-grained
// path -> 16B scattered stores became 64B HBM RMWs (WRITE_SIZE 57.7 MB vs
// 20.5 logical) and attn became bound by that traffic (85 us).  v15 keeps
// the split-K schedule but puts partials in CACHED workspace (xb+wat
// regions, dead after gemm1): only qtiles 20..31 split (768 partials,
// 12 MB f32 + 384 KB ml).  Critical chain: 20 iterations (qtile 19).
// Grid 1408 = 8 XCD x 4 groups x 44 items, LPT-ordered via ITEMS table.
#define QB 64
#define KB 64
#define QSCALE 0.18033688f   // 0.125 * log2(e)

// item code = qtile*4 + khalf*2 + split, sorted by length descending (LPT)
__device__ __constant__ unsigned char ITEMS[44] = {
  76, 72, 68, 64,                 // unsplit q19..q16 (len 20..17)
  125, 127, 121, 60,              // 31h0,31h1,30h0 (16), u15 (16)
  123, 117, 119, 113, 56,         // 30h1,29h0,29h1,28h0 (15), u14
  115, 109, 111, 105, 52,         // 28h1,27h0,27h1,26h0 (14), u13
  107, 101, 103, 97, 48,          // 26h1,25h0,25h1,24h0 (13), u12
  99, 93, 95, 89, 44,             // 24h1,23h0,23h1,22h0 (12), u11
  91, 85, 87, 81, 40,             // 22h1,21h0,21h1,20h0 (11), u10
  83, 36,                         // 20h1 (10), u9
  32, 28, 24, 20, 16, 12, 8, 4, 0 // u8..u0
};

__global__ __launch_bounds__(256, 4)
void attn_mfma(const __bf16* __restrict__ qkv, __bf16* __restrict__ y,
               float* __restrict__ pO, float* __restrict__ pml) {
  __shared__ __align__(16) __bf16 Ks[2][KB][64];   // 16 KB
  __shared__ __align__(16) __bf16 Vs[2][4096];     // 16 KB

  const int tid  = threadIdx.x;
  const int lane = tid & 63;
  const int w    = tid >> 6;

  // ---- work-item decode: 1408 blocks = 8 XCD x 4 groups x 44 items ----
  const int bid = blockIdx.x;                 // 0..1407
  const int xcd = bid & 7;
  const int j   = bid >> 3;                   // 0..175
  const int g   = xcd * 4 + j / 44;           // (b,h) group 0..31
  const int idx = j % 44;

  const int code  = ITEMS[idx];
  const bool split = code & 1;
  const int khalf = (code >> 1) & 1;
  const int qtile = code >> 2;

  int it0, it1;
  bool diag;
  if (!split) {
    it0 = 0; it1 = qtile + 1; diag = true;
  } else {
    const int half = (qtile + 2) >> 1;        // ceil((qtile+1)/2)
    it0 = khalf ? half : 0;
    it1 = khalf ? qtile + 1 : half;
    diag = (khalf == 1);
  }
  const int h = g & 15, b = g >> 4;
  const int pidx = split ? ((g * 12 + (qtile - 20)) * 2 + khalf) : 0;

  const __bf16* base = qkv + (size_t)b * S_LEN * QKV_LD;

  const int l31 = lane & 31;
  const int hl  = lane >> 5;          // lane half (0/1)
  const int qh  = w >> 1;             // q-half of the 64-row tile
  const int kh  = w & 1;              // k-half of each 64-key tile

  // tr_read per-lane base: column (lane&15) of the [4][16] subtile; the
  // db/sk selection comes from the address (law verified against v10).
  const int voff32 = ((lane >> 4) & 1) * 2048 + hl * 128 + (lane & 15) * 8
                   + kh * 1024;

  auto stageK = [&](int j0, int buf) {
    #pragma unroll
    for (int jj = 0; jj < 2; jj++) {
      const int cid = w * 128 + jj * 64 + lane;    // chunk 0..511
      const int r = cid >> 3, pc = cid & 7;
      const int lc = pc ^ (r & 7);                 // inverse swizzle on source
      gl_lds16(base + (size_t)(j0 + r) * QKV_LD + EMB + h * DH + lc * 8,
               (char*)&Ks[buf][0][0] + (w * 128 + jj * 64) * 16);
    }
  };
  auto stageV = [&](int j0, int buf) {
    #pragma unroll
    for (int jj = 0; jj < 2; jj++) {
      const int cid = w * 128 + jj * 64 + lane;
      const int db = cid >> 7, sk = (cid >> 3) & 15;
      const int jr = (cid >> 1) & 3, ch = cid & 1;
      gl_lds16(base + (size_t)(j0 + sk * 4 + jr) * QKV_LD + 2 * EMB + h * DH
                    + db * 16 + ch * 8,
               (char*)&Vs[buf][0] + (w * 128 + jj * 64) * 16);
    }
  };

  const int qbase = qtile * QB;
  const int q = qbase + qh * 32 + l31;           // this lane's q row

  // Q B-fragments (col=q, k_hw=d): qf[dq][i] = Q[q][dq*16 + hl*8 + i]
  bf16x8 qf[4];
  {
    const __bf16* qp = base + (size_t)q * QKV_LD + h * DH;
    #pragma unroll
    for (int dq = 0; dq < 4; dq++) {
      bf16x8 v = *(const bf16x8*)(qp + dq * 16 + hl * 8);
      #pragma unroll
      for (int i2 = 0; i2 < 8; i2++) qf[dq][i2] = (__bf16)((float)v[i2] * QSCALE);
    }
  }

  f32x16 o_acc[2];
  #pragma unroll
  for (int d2 = 0; d2 < 2; d2++)
    #pragma unroll
    for (int r = 0; r < 16; r++) o_acc[d2][r] = 0.f;
  float m = -1e30f, l = 0.f;

  // Process one K-tile: QK^T -> (masked?) online softmax -> PV.
  auto process = [&](int cur, int j0, bool masked) {
    // ---- S^T = K Q (32k x 32q, chained over d) ----
    // s[reg]: k = j0 + kh*32 + (reg&3) + 8*(reg>>2) + 4*hl, q = l31.
    f32x16 s;
    #pragma unroll
    for (int r = 0; r < 16; r++) s[r] = 0.f;
    const int krow = kh * 32 + l31;
    __builtin_amdgcn_s_setprio(1);
    #pragma unroll
    for (int dq = 0; dq < 4; dq++) {
      bf16x8 kf = *(const bf16x8*)&Ks[cur][krow][((dq * 2 + hl) ^ (krow & 7)) * 8];
      s = __builtin_amdgcn_mfma_f32_32x32x16_bf16(kf, qf[dq], s, 0, 0, 0);
    }
    __builtin_amdgcn_s_setprio(0);

    if (masked) {
      const int lim = q - j0 - kh * 32 - 4 * hl;   // keep if (reg&3)+8*(reg>>2) <= lim
      #pragma unroll
      for (int r = 0; r < 16; r++) {
        const int kl = (r & 3) + 8 * (r >> 2);
        if (kl > lim) s[r] = -2e30f;    // -2e30: exp2(s-m)==0 even when m=-1e30
      }
    }

    // ---- max reduce (in-lane tree + ONE cross-half shuffle) ----
    float tmax = s[0];
    #pragma unroll
    for (int r = 1; r < 16; r++) tmax = fmaxf(tmax, s[r]);
    tmax = fmaxf(tmax, __shfl_xor(tmax, 32));

    const bool grow = !__all(tmax <= m + 8.0f);
    float corr = 1.f;
    if (grow) {
      const float mnew = fmaxf(m, tmax);
      corr = __builtin_amdgcn_exp2f(m - mnew);
      m = mnew;
    }

    // ---- issue all 8 V^T transpose reads; latency hides under exp phase ----
    const unsigned vb =
        (unsigned)(uintptr_t)(__attribute__((address_space(3))) char*)(&Vs[cur][0])
        + (unsigned)voff32;
    u32x2 tv[8];
    asm volatile("ds_read_b64_tr_b16 %0, %1 offset:0"    : "=v"(tv[0]) : "v"(vb));
    asm volatile("ds_read_b64_tr_b16 %0, %1 offset:256"  : "=v"(tv[1]) : "v"(vb));
    asm volatile("ds_read_b64_tr_b16 %0, %1 offset:512"  : "=v"(tv[2]) : "v"(vb));
    asm volatile("ds_read_b64_tr_b16 %0, %1 offset:768"  : "=v"(tv[3]) : "v"(vb));
    asm volatile("ds_read_b64_tr_b16 %0, %1 offset:4096" : "=v"(tv[4]) : "v"(vb));
    asm volatile("ds_read_b64_tr_b16 %0, %1 offset:4352" : "=v"(tv[5]) : "v"(vb));
    asm volatile("ds_read_b64_tr_b16 %0, %1 offset:4608" : "=v"(tv[6]) : "v"(vb));
    asm volatile("ds_read_b64_tr_b16 %0, %1 offset:4864" : "=v"(tv[7]) : "v"(vb));

    // ---- exp2 + in-lane psum (VALU; covers the tr_read latency) ----
    float psum = 0.f;
    #pragma unroll
    for (int r = 0; r < 16; r++) {
      float p = __builtin_amdgcn_exp2f(s[r] - m);
      s[r] = p;
      psum += p;
    }

    // ---- P^T B-frags: fully in-lane (shared sigma with the A-side) ----
    bf16x8 pb0, pb1;
    #pragma unroll
    for (int i2 = 0; i2 < 8; i2++) {
      pb0[i2] = (__bf16)s[i2];
      pb1[i2] = (__bf16)s[8 + i2];
    }

    // ---- O-rescale must precede PV; l-update deferred past PV ----
    if (grow) {
      #pragma unroll
      for (int d2 = 0; d2 < 2; d2++)
        #pragma unroll
        for (int r = 0; r < 16; r++) o_acc[d2][r] *= corr;
    }

    // ---- single drain, then 4 back-to-back PV MFMAs ----
    asm volatile("s_waitcnt lgkmcnt(0)");
    __builtin_amdgcn_sched_barrier(0);
    __builtin_amdgcn_s_setprio(1);
    #pragma unroll
    for (int d2 = 0; d2 < 2; d2++) {
      bf16x8 a0, a1;
      ((u32x2*)&a0)[0] = tv[d2 * 4 + 0]; ((u32x2*)&a0)[1] = tv[d2 * 4 + 1];
      ((u32x2*)&a1)[0] = tv[d2 * 4 + 2]; ((u32x2*)&a1)[1] = tv[d2 * 4 + 3];
      o_acc[d2] = __builtin_amdgcn_mfma_f32_32x32x16_bf16(a0, pb0, o_acc[d2], 0, 0, 0);
      o_acc[d2] = __builtin_amdgcn_mfma_f32_32x32x16_bf16(a1, pb1, o_acc[d2], 0, 0, 0);
    }
    __builtin_amdgcn_s_setprio(0);

    // ---- l-update (off the PV critical path) ----
    psum += __shfl_xor(psum, 32);
    l = grow ? (l * corr + psum) : (l + psum);
  };

  // prologue: stage first tile of this item's K-range
  stageK(it0 * KB, 0);
  stageV(it0 * KB, 0);
  __syncthreads();

  // main loop: iterations it0..it1-2 unmasked, prefetching next
  const int nt = it1 - it0;
  #pragma unroll 1
  for (int tt = 0; tt < nt - 1; tt++) {
    const int cur = tt & 1;
    stageK((it0 + tt + 1) * KB, cur ^ 1);
    stageV((it0 + tt + 1) * KB, cur ^ 1);
    process(cur, (it0 + tt) * KB, false);
    __syncthreads();   // staged loads drained; buf cur free for reuse
  }

  // final tile (masked iff this item covers the diagonal)
  process((nt - 1) & 1, (it1 - 1) * KB, diag);

  // ---- kh-pair merge through LDS, then epilogue by kh=0 waves ----
  __syncthreads();     // all waves done with Ks/Vs; reuse as exchange space
  float* exO  = (float*)&Vs[0][0];      // [32 rows][128 slots] f32 = 16 KB
  float* exML = (float*)&Ks[0][0][0];   // [2][128] f32
  const int slot = qh * 64 + lane;
  if (kh) {
    #pragma unroll
    for (int r = 0; r < 16; r++) {
      exO[r * 128 + slot]        = o_acc[0][r];
      exO[(16 + r) * 128 + slot] = o_acc[1][r];
    }
    exML[slot]       = m;
    exML[128 + slot] = l;
  }
  __syncthreads();
  if (!kh) {
    const float m1  = exML[slot];
    const float l1v = exML[128 + slot];
    const float mm = fmaxf(m, m1);
    const float c0 = __builtin_amdgcn_exp2f(m - mm);
    const float c1 = __builtin_amdgcn_exp2f(m1 - mm);
    const float lsum = l * c0 + l1v * c1;
    if (split) {
      // unnormalized f32 partial + (m,l) for attn_merge (cached workspace)
      float* prow = pO + (size_t)pidx * 4096 + (size_t)(qh * 32 + l31) * 64;
      #pragma unroll
      for (int d2 = 0; d2 < 2; d2++)
        #pragma unroll
        for (int rq = 0; rq < 4; rq++) {
          f32x4 o4;
          #pragma unroll
          for (int jj = 0; jj < 4; jj++) {
            const int r = rq * 4 + jj;
            o4[jj] = o_acc[d2][r] * c0 + exO[(d2 * 16 + r) * 128 + slot] * c1;
          }
          *(f32x4*)&prow[d2 * 32 + rq * 8 + hl * 4] = o4;
        }
      if (!hl) {
        pml[(size_t)pidx * 128 + qh * 32 + l31]      = mm;
        pml[(size_t)pidx * 128 + 64 + qh * 32 + l31] = lsum;
      }
    } else {
      const float inv = 1.f / lsum;
      __bf16* yrow = y + ((size_t)(b * S_LEN + q)) * EMB + h * DH;
      #pragma unroll
      for (int d2 = 0; d2 < 2; d2++)
        #pragma unroll
        for (int rq = 0; rq < 4; rq++) {
          bf16x4 o4;
          #pragma unroll
          for (int jj = 0; jj < 4; jj++) {
            const int r = rq * 4 + jj;
            float v = (o_acc[d2][r] * c0 + exO[(d2 * 16 + r) * 128 + slot] * c1) * inv;
            o4[jj] = (__bf16)v;
          }
          // d = d2*32 + rq*8 + hl*4 + jj
          *(bf16x4*)&yrow[d2 * 32 + rq * 8 + hl * 4] = o4;
        }
    }
  }
}

// ---------------- merge the two K-half partials of qtiles 20..31 ----------
__global__ __launch_bounds__(256)
void attn_merge(const float* __restrict__ pO, const float* __restrict__ pml,
                __bf16* __restrict__ y) {
  const int mid = blockIdx.x;            // 0..383
  const int g = mid / 12, qrel = mid % 12;
  const int qt = 20 + qrel;
  const int b = g >> 4, h = g & 15;
  const int p0 = (g * 12 + qrel) * 2, p1 = p0 + 1;
  const int row = threadIdx.x >> 2;            // 0..63
  const int d0  = (threadIdx.x & 3) * 16;      // 0,16,32,48

  const float mA = pml[(size_t)p0 * 128 + row];
  const float lA = pml[(size_t)p0 * 128 + 64 + row];
  const float mB = pml[(size_t)p1 * 128 + row];
  const float lB = pml[(size_t)p1 * 128 + 64 + row];
  const float mm = fmaxf(mA, mB);
  const float cA = __builtin_amdgcn_exp2f(mA - mm);
  const float cB = __builtin_amdgcn_exp2f(mB - mm);
  const float inv = 1.f / (lA * cA + lB * cB);

  const float* OA = pO + (size_t)p0 * 4096 + (size_t)row * 64 + d0;
  const float* OB = pO + (size_t)p1 * 4096 + (size_t)row * 64 + d0;
  __bf16* yr = y + ((size_t)(b * S_LEN + qt * 64 + row)) * EMB + h * DH + d0;
  #pragma unroll
  for (int i = 0; i < 4; i++) {
    f32x4 va = *(const f32x4*)(OA + i * 4);
    f32x4 vb = *(const f32x4*)(OB + i * 4);
    bf16x4 o;
    #pragma unroll
    for (int jj = 0; jj < 4; jj++)
      o[jj] = (__bf16)((va[jj] * cA + vb[jj] * cB) * inv);
    *(bf16x4*)(yr + i * 4) = o;
  }
}

// ---------------- Launch ----------------
extern "C" void kernel_launch(void* const* d_in, const int* in_sizes, int n_in,
                              void* d_out, int out_size, void* d_ws, size_t ws_size,
                              hipStream_t stream) {
  const float* x      = (const float*)d_in[0];  // (B, S, E)
  const float* w_attn = (const float*)d_in[1];  // (E, 3E)
  const float* w_proj = (const float*)d_in[2];  // (E, E)
  float* out = (float*)d_out;                   // (B, S, E)

  const int B = in_sizes[0] / (S_LEN * EMB);    // = 2
  const int M = B * S_LEN;                      // 4096

  // bf16 workspace layout
  __bf16* xb   = (__bf16*)d_ws;                       // M x E          (8 MB)
  __bf16* wat  = xb  + (size_t)M * EMB;               // 3E x E transp  (6 MB)
  __bf16* wpt  = wat + (size_t)QKV_LD * EMB;          // E x E transp   (2 MB)
  __bf16* qkvb = wpt + (size_t)EMB * EMB;             // M x 3E         (24 MB)
  __bf16* yb   = qkvb + (size_t)M * QKV_LD;           // M x E          (8 MB)

  // split-K partials live in CACHED ws: xb+wat (14 MB contiguous, dead after
  // gemm1).  pO = 768 x 4096 f32 = 12 MB; pml = 768 x 128 f32 = 384 KB.
  float* pO  = (float*)d_ws;
  float* pml = pO + (size_t)768 * 4096;

  // 0) fused prep: cast + both weight transposes in one launch
  {
    int n8 = (M * EMB) / 8;   // 524288 -> 2048 cast blocks
    prep_fused<<<dim3(3072), 256, 0, stream>>>(x, xb, w_attn, wat, w_proj, wpt, n8);
  }

  // 1) qkv = x @ w_attn  (bf16 out, TN=128: grid 768 = 3 blocks/CU)
  dim3 g1(QKV_LD / 128, M / TM);
  gemm_bf16_mfma<__bf16, 128><<<g1, 256, 0, stream>>>(xb, wat, qkvb, M, QKV_LD, EMB);

  // 2) y = causal_attention(qkv)  [v15: split-K qtiles 20..31, cached pO]
  attn_mfma<<<dim3(1408), 256, 0, stream>>>(qkvb, yb, pO, pml);
  attn_merge<<<dim3(384), 256, 0, stream>>>(pO, pml, yb);

  // 3) out = y @ w_proj  (f32 out, TN=64: grid 512 = 2 blocks/CU)
  dim3 g3(EMB / 64, M / TM);
  gemm_bf16_mfma<float, 64><<<g3, 256, 0, stream>>>(yb, wpt, out, M, EMB, EMB);
}